// Round 8
// baseline (275.396 us; speedup 1.0000x reference)
//
#include <hip/hip_runtime.h>

#define NGRAPH 256
#define NN     128   // nodes per graph
#define NT     16    // templates
#define NM     10    // template nodes
#define OUTER_IT 5
#define SINK_IT  20

// K = exp(-20*tens) = exp2(-20*log2(e)*tens)
#define SC1  28.85390081777927f    // 20*log2(e)
#define SC2  57.70780163555854f    // 40*log2(e)

typedef unsigned long long u64;
typedef float v2f __attribute__((ext_vector_type(2)));
typedef float v4f __attribute__((ext_vector_type(4)));
typedef _Float16 half8 __attribute__((ext_vector_type(8)));

static __device__ __forceinline__ v2f pkfma(v2f a, v2f b, v2f c) {
  return __builtin_elementwise_fma(a, b, c);
}
static __device__ __forceinline__ v2f bc2(float s) { return (v2f){s, s}; }

// DPP xor-butterfly add within a 16-lane row (masks {1,2,7,15} span (Z2)^4).
template <int CTRL>
__device__ __forceinline__ float dpp_add(float a) {
  int t = __builtin_amdgcn_update_dpp(0, __float_as_int(a), CTRL, 0xf, 0xf, true);
  return a + __int_as_float(t);
}
// Sum over each 32-lane group; result broadcast to all lanes of the group.
__device__ __forceinline__ float allsum32(float x) {
  x = dpp_add<0xB1>(x);    // quad_perm xor 1
  x = dpp_add<0x4E>(x);    // quad_perm xor 2
  x = dpp_add<0x141>(x);   // row_half_mirror: xor 7
  x = dpp_add<0x140>(x);   // row_mirror: xor 15
  int sw = __builtin_amdgcn_ds_swizzle(__float_as_int(x), 0x401F); // xor 16
  return x + __int_as_float(sw);
}

// 32 lanes per (graph b, template t) pair, 2 pairs per 64-thread single-wave
// block. Sinkhorn: lane owns 4 rows r = sub + 32*c of K (registers, fp32
// pk-packed over the 10-column axis). S = C1@P computed by MFMA
// (f32_16x16x32_f16): C1 bitmask expanded once into resident A-fragments;
// P kept column-major f16 in LDS (B-frags = aligned b128); D (C-layout)
// round-trips through LDS into the Sinkhorn row layout.
__global__ __launch_bounds__(64, 2)
void tgw_kernel(const int* __restrict__ ei,
                const float* __restrict__ tadj,
                const float* __restrict__ q0g,
                float* __restrict__ out,
                int E, int ne) {
  const int lane = threadIdx.x;
  const int p    = lane >> 5;        // pair slot 0/1 (Sinkhorn layout)
  const int sub  = lane & 31;
  const int mrow = lane & 15;        // MFMA m / n / col index
  const int quad = lane >> 4;        // MFMA quad 0..3
  const int b    = blockIdx.x >> 3;
  const int t0   = (blockIdx.x & 7) * 2;   // templates t0, t0+1

  __shared__ __align__(16) unsigned adj[NN][4];        // 2 KB bitmask
  __shared__ __align__(16) _Float16 Pt[2][16][136];    // P col-major f16, 8.5 KB
  __shared__ __align__(16) float Srow[2][NN][12];      // S row-major, 12 KB
  __shared__ __align__(16) v2f C2T[2][NM][6];          // SC2*C2 [m][jpair]
  __shared__ float q0s[2][NM];

  // ---- stage ----
  for (int i = lane; i < NN * 4; i += 64) (&adj[0][0])[i] = 0u;
  for (int i = lane; i < 2 * NM * 5; i += 64) {
    int tt = i / 50, r = i % 50, m = r / 5, jp = r % 5;
    const float* bp = tadj + (t0 + tt) * NM * NM + m;
    C2T[tt][m][jp] = (v2f){bp[(2 * jp) * NM], bp[(2 * jp + 1) * NM]} * SC2;
  }
  if (lane < 2 * NM) q0s[lane / NM][lane % NM] = q0g[t0 * NM + lane];
  __syncthreads();

  // symmetric 0/1 adjacency from the edge list (dups/self-loops harmless)
  const int* srcp = ei;
  const int* dstp = ei + E;
  const int ebase = b * ne;
  for (int e = lane; e < ne; e += 64) {
    int s = srcp[ebase + e] & (NN - 1);
    int d = dstp[ebase + e] & (NN - 1);
    atomicOr(&adj[s][d >> 5], 1u << (d & 31));
    atomicOr(&adj[d][s >> 5], 1u << (s & 31));
  }
  __syncthreads();

  // ---- per-pair constants ----
  float qv[NM];
  {
    float mx = q0s[p][0];
    #pragma unroll
    for (int j = 1; j < NM; ++j) mx = fmaxf(mx, q0s[p][j]);
    float s = 0.f;
    #pragma unroll
    for (int j = 0; j < NM; ++j) { qv[j] = __expf(q0s[p][j] - mx); s += qv[j]; }
    float inv = __builtin_amdgcn_rcpf(s);
    #pragma unroll
    for (int j = 0; j < NM; ++j) qv[j] *= inv;
  }
  v2f q2[5];
  #pragma unroll
  for (int jp = 0; jp < 5; ++jp) q2[jp] = (v2f){qv[2 * jp], qv[2 * jp + 1]};

  // fq2[jp] = -SC1 * f2q[jpair]
  v2f fq2[5];
  {
    #pragma unroll
    for (int jp = 0; jp < 5; ++jp) fq2[jp] = (v2f){0.f, 0.f};
    #pragma unroll
    for (int m = 0; m < NM; ++m) {
      v2f qb = bc2(qv[m]);
      #pragma unroll
      for (int jp = 0; jp < 5; ++jp) {
        v2f c = C2T[p][m][jp];
        fq2[jp] = pkfma(c * c, qb, fq2[jp]);
      }
    }
    const float f = -1.0f / (4.0f * SC1);   // -SC1/SC2^2
    #pragma unroll
    for (int jp = 0; jp < 5; ++jp) fq2[jp] *= f;
  }

  const float pw = 1.0f / 128.0f;
  float f1p[4], m1f1[4];
  #pragma unroll
  for (int c = 0; c < 4; ++c) {
    uint4 mm = *(const uint4*)&adj[sub + 32 * c][0];
    u64 m0 = mm.x | ((u64)mm.y << 32), m1 = mm.z | ((u64)mm.w << 32);
    f1p[c]  = (float)(__popcll(m0) + __popcll(m1)) * pw;   // C1*C1 == C1
    m1f1[c] = -SC1 * f1p[c];
  }

  // ---- build resident A-fragments of C1 (once; C1 static per block) ----
  // A[m][k], m = mrow, k = quad*8 + j (+Kt*32): bits of byte `quad` of
  // adj[Mt*16+mrow][Kt]; expand to f16 1.0/0.0 pairs.
  half8 Afrag[8][4];
  #pragma unroll
  for (int Mt = 0; Mt < 8; ++Mt) {
    #pragma unroll
    for (int Kt = 0; Kt < 4; ++Kt) {
      unsigned w  = adj[Mt * 16 + mrow][Kt];
      unsigned by = (w >> (quad * 8)) & 0xFFu;
      union { unsigned u[4]; half8 h; } cv;
      #pragma unroll
      for (int t = 0; t < 4; ++t) {
        unsigned b0 = (by >> (2 * t)) & 1u;
        unsigned b1 = (by >> (2 * t + 1)) & 1u;
        cv.u[t] = (b0 ? 0x3C00u : 0u) | (b1 ? 0x3C000000u : 0u);
      }
      Afrag[Mt][Kt] = cv.h;
    }
  }

  // MFMA pass: S = C1 @ P for both pairs -> Srow (row-major f32)
  auto mfmaPass = [&]() {
    #pragma unroll
    for (int pp = 0; pp < 2; ++pp) {
      v4f acc[8];
      #pragma unroll
      for (int Mt = 0; Mt < 8; ++Mt) acc[Mt] = (v4f){0.f, 0.f, 0.f, 0.f};
      #pragma unroll
      for (int Kt = 0; Kt < 4; ++Kt) {
        half8 bf = *(const half8*)&Pt[pp][mrow][Kt * 32 + quad * 8];
        #pragma unroll
        for (int Mt = 0; Mt < 8; ++Mt)
          acc[Mt] = __builtin_amdgcn_mfma_f32_16x16x32_f16(
              Afrag[Mt][Kt], bf, acc[Mt], 0, 0, 0);
      }
      if (mrow < NM) {
        #pragma unroll
        for (int Mt = 0; Mt < 8; ++Mt) {
          int mb = Mt * 16 + quad * 4;
          Srow[pp][mb + 0][mrow] = acc[Mt].x;
          Srow[pp][mb + 1][mrow] = acc[Mt].y;
          Srow[pp][mb + 2][mrow] = acc[Mt].z;
          Srow[pp][mb + 3][mrow] = acc[Mt].w;
        }
      }
    }
    __syncthreads();
  };

  // arg2[c][jp] = -SC1*tens (packed over jpairs)
  auto costFromS = [&](v2f Sm[4][5], v2f arg2[4][5]) {
    #pragma unroll
    for (int c = 0; c < 4; ++c)
      #pragma unroll
      for (int jp = 0; jp < 5; ++jp) arg2[c][jp] = fq2[jp] + bc2(m1f1[c]);
    #pragma unroll
    for (int m = 0; m < NM; ++m) {
      v4f X = *(const v4f*)&C2T[p][m][0];
      v4f Y = *(const v4f*)&C2T[p][m][2];
      v2f Z = *(const v2f*)&C2T[p][m][4];
      #pragma unroll
      for (int c = 0; c < 4; ++c) {
        float sv = (m & 1) ? Sm[c][m >> 1].y : Sm[c][m >> 1].x;
        v2f sb = bc2(sv);
        arg2[c][0] = pkfma(sb, X.xy, arg2[c][0]);
        arg2[c][1] = pkfma(sb, X.zw, arg2[c][1]);
        arg2[c][2] = pkfma(sb, Y.xy, arg2[c][2]);
        arg2[c][3] = pkfma(sb, Y.zw, arg2[c][3]);
        arg2[c][4] = pkfma(sb, Z,    arg2[c][4]);
      }
    }
  };
  auto loadS = [&](v2f Sm[4][5]) {
    #pragma unroll
    for (int c = 0; c < 4; ++c) {
      const float* sr = &Srow[p][sub + 32 * c][0];
      v4f A = *(const v4f*)sr;
      v4f B = *(const v4f*)(sr + 4);
      v2f C = *(const v2f*)(sr + 8);
      Sm[c][0] = A.xy; Sm[c][1] = A.zw; Sm[c][2] = B.xy; Sm[c][3] = B.zw; Sm[c][4] = C;
    }
  };

  v2f K2[4][5], v2[5], arg2[4][5];
  float uu[4];

  for (int o = 0; o < OUTER_IT; ++o) {
    // ---- cost -> arg2 -> K = exp2(arg) ----
    v2f Sm[4][5];
    if (o == 0) {
      // P0 = p q^T => S[c][m] = f1p[c]*q[m]
      #pragma unroll
      for (int c = 0; c < 4; ++c)
        #pragma unroll
        for (int h = 0; h < 5; ++h) Sm[c][h] = bc2(f1p[c]) * q2[h];
    } else {
      mfmaPass();          // Pt (from previous outer) -> Srow
      loadS(Sm);
    }
    costFromS(Sm, arg2);
    #pragma unroll
    for (int c = 0; c < 4; ++c)
      #pragma unroll
      for (int jp = 0; jp < 5; ++jp)
        K2[c][jp] = (v2f){exp2f(arg2[c][jp].x), exp2f(arg2[c][jp].y)};

    // ---- Sinkhorn (v starts at ones) ----
    #pragma unroll
    for (int jp = 0; jp < 5; ++jp) v2[jp] = (v2f){1.f, 1.f};
    for (int it = 0; it < SINK_IT; ++it) {
      #pragma unroll
      for (int c = 0; c < 4; ++c) {
        v2f d2 = K2[c][0] * v2[0];
        d2 = pkfma(K2[c][1], v2[1], d2);
        d2 = pkfma(K2[c][2], v2[2], d2);
        d2 = pkfma(K2[c][3], v2[3], d2);
        d2 = pkfma(K2[c][4], v2[4], d2);
        uu[c] = pw * __builtin_amdgcn_rcpf(d2.x + d2.y);
      }
      #pragma unroll
      for (int jp = 0; jp < 5; ++jp) {
        v2f w2 = K2[0][jp] * bc2(uu[0]);
        w2 = pkfma(K2[1][jp], bc2(uu[1]), w2);
        w2 = pkfma(K2[2][jp], bc2(uu[2]), w2);
        w2 = pkfma(K2[3][jp], bc2(uu[3]), w2);
        float cx = allsum32(w2.x);
        float cy = allsum32(w2.y);
        v2[jp] = (v2f){q2[jp].x * __builtin_amdgcn_rcpf(cx),
                       q2[jp].y * __builtin_amdgcn_rcpf(cy)};
      }
    }

    // ---- P = diag(u) K diag(v) -> Pt (col-major f16) ----
    __syncthreads();   // drain prior-pass B-frag reads before overwrite
    #pragma unroll
    for (int c = 0; c < 4; ++c) {
      const int k = sub + 32 * c;
      v2f ub = bc2(uu[c]);
      v2f x0 = K2[c][0] * ub * v2[0];
      v2f x1 = K2[c][1] * ub * v2[1];
      v2f x2 = K2[c][2] * ub * v2[2];
      v2f x3 = K2[c][3] * ub * v2[3];
      v2f x4 = K2[c][4] * ub * v2[4];
      Pt[p][0][k] = (_Float16)x0.x; Pt[p][1][k] = (_Float16)x0.y;
      Pt[p][2][k] = (_Float16)x1.x; Pt[p][3][k] = (_Float16)x1.y;
      Pt[p][4][k] = (_Float16)x2.x; Pt[p][5][k] = (_Float16)x2.y;
      Pt[p][6][k] = (_Float16)x3.x; Pt[p][7][k] = (_Float16)x3.y;
      Pt[p][8][k] = (_Float16)x4.x; Pt[p][9][k] = (_Float16)x4.y;
    }
    __syncthreads();
  }

  // ---- GW = sum_ij tens(P)_ij * P_ij,  tens = arg * (-1/SC1) ----
  float acc = 0.f;
  {
    v2f Sm[4][5];
    mfmaPass();
    loadS(Sm);
    costFromS(Sm, arg2);
    const v2f nf = bc2(-1.0f / SC1);
    v2f acc2 = (v2f){0.f, 0.f};
    #pragma unroll
    for (int c = 0; c < 4; ++c) {
      v2f ub = bc2(uu[c]);
      #pragma unroll
      for (int jp = 0; jp < 5; ++jp) {
        v2f Pv = K2[c][jp] * ub * v2[jp];
        acc2 = pkfma(arg2[c][jp] * nf, Pv, acc2);
      }
    }
    acc = acc2.x + acc2.y;
  }
  float total = allsum32(acc);
  if (sub == 0) out[b * NT + t0 + p] = total;
}

extern "C" void kernel_launch(void* const* d_in, const int* in_sizes, int n_in,
                              void* d_out, int out_size, void* d_ws, size_t ws_size,
                              hipStream_t stream) {
  // inputs: 0 x(f32, unused) 1 edge_index(int32) 2 batch(int32, unused)
  //         3 tplt_adjacencies(f32) 4 tplt_features(f32, unused) 5 q0(f32)
  const int* ei   = (const int*)d_in[1];
  const float* c2 = (const float*)d_in[3];
  const float* q0 = (const float*)d_in[5];
  float* out      = (float*)d_out;
  const int E  = in_sizes[1] / 2;
  const int ne = E / NGRAPH;
  tgw_kernel<<<dim3(NGRAPH * 8), dim3(64), 0, stream>>>(ei, c2, q0, out, E, ne);
}

// Round 9
// 222.195 us; speedup vs baseline: 1.2394x; 1.2394x over previous
//
#include <hip/hip_runtime.h>

#define NGRAPH 256
#define NN     128   // nodes per graph
#define NT     16    // templates
#define NM     10    // template nodes
#define OUTER_IT 5
#define SINK_IT  20

// K = exp(-20*tens) = exp2(-20*log2(e)*tens)
#define SC1  28.85390081777927f    // 20*log2(e)
#define SC2  57.70780163555854f    // 40*log2(e)

typedef unsigned long long u64;
typedef float v2f __attribute__((ext_vector_type(2)));
typedef float v4f __attribute__((ext_vector_type(4)));

static __device__ __forceinline__ v2f pkfma(v2f a, v2f b, v2f c) {
  return __builtin_elementwise_fma(a, b, c);
}
static __device__ __forceinline__ v2f bc2(float s) { return (v2f){s, s}; }

// DPP add step
template <int CTRL>
__device__ __forceinline__ float dpp_add(float a) {
  int t = __builtin_amdgcn_update_dpp(0, __float_as_int(a), CTRL, 0xf, 0xf, true);
  return a + __int_as_float(t);
}
// 64-lane sum (R2-verified chain): shr1,2,4,8 + bcast15 + bcast31 + readlane63
__device__ __forceinline__ float allsum64(float x) {
  x = dpp_add<0x111>(x);  // row_shr:1
  x = dpp_add<0x112>(x);  // row_shr:2
  x = dpp_add<0x114>(x);  // row_shr:4
  x = dpp_add<0x118>(x);  // row_shr:8
  x = dpp_add<0x142>(x);  // row_bcast:15
  x = dpp_add<0x143>(x);  // row_bcast:31
  return __int_as_float(__builtin_amdgcn_readlane(__float_as_int(x), 63));
}

// One 64-lane wave (= one block) per (graph b, template t) pair; lane owns
// rows lane and lane+64 of K/P. 4096 blocks -> 16 waves/CU (4/SIMD).
// Adjacency: LDS bitmask. P: LDS fp32, stride 12 floats. fp32 math packed
// 2-wide over the 10-column axis (v_pk_fma_f32).
__global__ __launch_bounds__(64, 4)
void tgw_kernel(const int* __restrict__ ei,
                const float* __restrict__ tadj,
                const float* __restrict__ q0g,
                float* __restrict__ out,
                int E, int ne) {
  const int lane = threadIdx.x;
  const int b    = blockIdx.x >> 4;
  const int t    = blockIdx.x & 15;

  __shared__ __align__(16) unsigned adj[NN][4];   // 2 KB
  __shared__ __align__(16) float Pls[NN][12];     // 6 KB
  __shared__ __align__(16) v2f C2T[NM][6];        // SC2*C2 [m][jpair], 480 B
  __shared__ float q0s[NM];

  // ---- stage ----
  {
    uint4 z = {0u, 0u, 0u, 0u};
    ((uint4*)adj)[lane]      = z;
    ((uint4*)adj)[lane + 64] = z;
  }
  if (lane < NM * 5) {
    int m = lane / 5, jp = lane % 5;
    const float* bp = tadj + t * NM * NM + m;
    C2T[m][jp] = (v2f){bp[(2 * jp) * NM], bp[(2 * jp + 1) * NM]} * SC2;
  }
  if (lane < NM) q0s[lane] = q0g[t * NM + lane];
  __syncthreads();

  // symmetric 0/1 adjacency from the edge list (dups/self-loops harmless)
  const int* srcp = ei;
  const int* dstp = ei + E;
  const int ebase = b * ne;
  for (int e = lane; e < ne; e += 64) {
    int s = srcp[ebase + e] & (NN - 1);
    int d = dstp[ebase + e] & (NN - 1);
    atomicOr(&adj[s][d >> 5], 1u << (d & 31));
    atomicOr(&adj[d][s >> 5], 1u << (s & 31));
  }
  __syncthreads();

  // ---- per-pair constants ----
  v2f q2[5];
  {
    float qv[NM];
    float mx = q0s[0];
    #pragma unroll
    for (int j = 1; j < NM; ++j) mx = fmaxf(mx, q0s[j]);
    float s = 0.f;
    #pragma unroll
    for (int j = 0; j < NM; ++j) { qv[j] = __expf(q0s[j] - mx); s += qv[j]; }
    float inv = __builtin_amdgcn_rcpf(s);
    #pragma unroll
    for (int jp = 0; jp < 5; ++jp)
      q2[jp] = (v2f){qv[2 * jp] * inv, qv[2 * jp + 1] * inv};
  }

  // fq2[jp] = -SC1*f2q pairs; qC2T[jp] = sum_m q[m]*C2T[m][jp] (o=0 analytic)
  v2f fq2[5], qC2T[5];
  {
    #pragma unroll
    for (int jp = 0; jp < 5; ++jp) { fq2[jp] = (v2f){0.f, 0.f}; qC2T[jp] = (v2f){0.f, 0.f}; }
    #pragma unroll
    for (int m = 0; m < NM; ++m) {
      float qm = (m & 1) ? q2[m >> 1].y : q2[m >> 1].x;
      v2f qb = bc2(qm);
      #pragma unroll
      for (int jp = 0; jp < 5; ++jp) {
        v2f c = C2T[m][jp];
        fq2[jp]  = pkfma(c * c, qb, fq2[jp]);
        qC2T[jp] = pkfma(c, qb, qC2T[jp]);
      }
    }
    const float f = -1.0f / (4.0f * SC1);   // -SC1/SC2^2
    #pragma unroll
    for (int jp = 0; jp < 5; ++jp) fq2[jp] *= f;
  }

  const float pw = 1.0f / 128.0f;
  float f1p[2], m1f1[2];
  #pragma unroll
  for (int c = 0; c < 2; ++c) {
    uint4 mm = *(const uint4*)&adj[lane + 64 * c][0];
    u64 m0 = mm.x | ((u64)mm.y << 32), m1 = mm.z | ((u64)mm.w << 32);
    f1p[c]  = (float)(__popcll(m0) + __popcll(m1)) * pw;   // C1*C1 == C1
    m1f1[c] = -SC1 * f1p[c];
  }

  // sparse gather S = (C1 @ P)[row r], packed pairs over m
  auto gatherRow = [&](int r, v2f* S2) {
    uint4 mm = *(const uint4*)&adj[r][0];
    u64 m0 = mm.x | ((u64)mm.y << 32), m1 = mm.z | ((u64)mm.w << 32);
    #pragma unroll
    for (int h = 0; h < 5; ++h) S2[h] = (v2f){0.f, 0.f};
    while (m0) {
      int k = (int)__builtin_ctzll(m0); m0 &= m0 - 1;
      const float* row = &Pls[k][0];
      v4f A = *(const v4f*)row;
      v4f B = *(const v4f*)(row + 4);
      v2f C = *(const v2f*)(row + 8);
      S2[0] += A.xy; S2[1] += A.zw; S2[2] += B.xy; S2[3] += B.zw; S2[4] += C;
    }
    while (m1) {
      int k = 64 + (int)__builtin_ctzll(m1); m1 &= m1 - 1;
      const float* row = &Pls[k][0];
      v4f A = *(const v4f*)row;
      v4f B = *(const v4f*)(row + 4);
      v2f C = *(const v2f*)(row + 8);
      S2[0] += A.xy; S2[1] += A.zw; S2[2] += B.xy; S2[3] += B.zw; S2[4] += C;
    }
  };

  // arg2[c][jp] = -SC1*tens, sharing the C2T loads across both rows
  auto costFromS = [&](v2f Sm[2][5], v2f arg2[2][5]) {
    #pragma unroll
    for (int c = 0; c < 2; ++c)
      #pragma unroll
      for (int jp = 0; jp < 5; ++jp) arg2[c][jp] = fq2[jp] + bc2(m1f1[c]);
    #pragma unroll
    for (int m = 0; m < NM; ++m) {
      v4f X = *(const v4f*)&C2T[m][0];   // jp 0,1
      v4f Y = *(const v4f*)&C2T[m][2];   // jp 2,3
      v2f Z = *(const v2f*)&C2T[m][4];   // jp 4
      #pragma unroll
      for (int c = 0; c < 2; ++c) {
        float sv = (m & 1) ? Sm[c][m >> 1].y : Sm[c][m >> 1].x;
        v2f sb = bc2(sv);
        arg2[c][0] = pkfma(sb, X.xy, arg2[c][0]);
        arg2[c][1] = pkfma(sb, X.zw, arg2[c][1]);
        arg2[c][2] = pkfma(sb, Y.xy, arg2[c][2]);
        arg2[c][3] = pkfma(sb, Y.zw, arg2[c][3]);
        arg2[c][4] = pkfma(sb, Z,    arg2[c][4]);
      }
    }
  };

  v2f K2[2][5], v2[5], arg2[2][5];
  float uu[2];

  for (int o = 0; o < OUTER_IT; ++o) {
    // ---- cost -> arg2 -> K = exp2(arg) ----
    if (o == 0) {
      // P0 = p q^T => sum_m S C2T = f1p[c]*qC2T
      #pragma unroll
      for (int c = 0; c < 2; ++c) {
        v2f fb = bc2(f1p[c]);
        v2f ob = bc2(m1f1[c]);
        #pragma unroll
        for (int jp = 0; jp < 5; ++jp)
          arg2[c][jp] = pkfma(fb, qC2T[jp], fq2[jp] + ob);
      }
    } else {
      v2f Sm[2][5];
      gatherRow(lane,      Sm[0]);
      gatherRow(lane + 64, Sm[1]);
      costFromS(Sm, arg2);
    }
    #pragma unroll
    for (int c = 0; c < 2; ++c)
      #pragma unroll
      for (int jp = 0; jp < 5; ++jp)
        K2[c][jp] = (v2f){exp2f(arg2[c][jp].x), exp2f(arg2[c][jp].y)};

    // ---- Sinkhorn (v starts at ones) ----
    #pragma unroll
    for (int jp = 0; jp < 5; ++jp) v2[jp] = (v2f){1.f, 1.f};
    for (int it = 0; it < SINK_IT; ++it) {
      #pragma unroll
      for (int c = 0; c < 2; ++c) {
        v2f d2 = K2[c][0] * v2[0];
        d2 = pkfma(K2[c][1], v2[1], d2);
        d2 = pkfma(K2[c][2], v2[2], d2);
        d2 = pkfma(K2[c][3], v2[3], d2);
        d2 = pkfma(K2[c][4], v2[4], d2);
        uu[c] = pw * __builtin_amdgcn_rcpf(d2.x + d2.y);
      }
      #pragma unroll
      for (int jp = 0; jp < 5; ++jp) {
        v2f w2 = K2[0][jp] * bc2(uu[0]);
        w2 = pkfma(K2[1][jp], bc2(uu[1]), w2);
        float cx = allsum64(w2.x);
        float cy = allsum64(w2.y);
        v2[jp] = (v2f){q2[jp].x * __builtin_amdgcn_rcpf(cx),
                       q2[jp].y * __builtin_amdgcn_rcpf(cy)};
      }
    }

    // ---- P = diag(u) K diag(v) -> LDS ----
    __syncthreads();   // single wave: drains prior LDS reads, ~free
    #pragma unroll
    for (int c = 0; c < 2; ++c) {
      v2f ub = bc2(uu[c]);
      v2f x0 = K2[c][0] * ub * v2[0];
      v2f x1 = K2[c][1] * ub * v2[1];
      v2f x2 = K2[c][2] * ub * v2[2];
      v2f x3 = K2[c][3] * ub * v2[3];
      v2f x4 = K2[c][4] * ub * v2[4];
      float* row = &Pls[lane + 64 * c][0];
      *(v4f*)row       = (v4f){x0.x, x0.y, x1.x, x1.y};
      *(v4f*)(row + 4) = (v4f){x2.x, x2.y, x3.x, x3.y};
      *(v2f*)(row + 8) = x4;
    }
    __syncthreads();
  }

  // ---- GW = sum_ij tens(P)_ij * P_ij,  tens = arg * (-1/SC1) ----
  float acc;
  {
    v2f Sm[2][5];
    gatherRow(lane,      Sm[0]);
    gatherRow(lane + 64, Sm[1]);
    costFromS(Sm, arg2);
    const v2f nf = bc2(-1.0f / SC1);
    v2f acc2 = (v2f){0.f, 0.f};
    #pragma unroll
    for (int c = 0; c < 2; ++c) {
      v2f ub = bc2(uu[c]);
      #pragma unroll
      for (int jp = 0; jp < 5; ++jp) {
        v2f Pv = K2[c][jp] * ub * v2[jp];
        acc2 = pkfma(arg2[c][jp] * nf, Pv, acc2);
      }
    }
    acc = acc2.x + acc2.y;
  }
  float total = allsum64(acc);
  if (lane == 0) out[b * NT + t] = total;
}

extern "C" void kernel_launch(void* const* d_in, const int* in_sizes, int n_in,
                              void* d_out, int out_size, void* d_ws, size_t ws_size,
                              hipStream_t stream) {
  // inputs: 0 x(f32, unused) 1 edge_index(int32) 2 batch(int32, unused)
  //         3 tplt_adjacencies(f32) 4 tplt_features(f32, unused) 5 q0(f32)
  const int* ei   = (const int*)d_in[1];
  const float* c2 = (const float*)d_in[3];
  const float* q0 = (const float*)d_in[5];
  float* out      = (float*)d_out;
  const int E  = in_sizes[1] / 2;
  const int ne = E / NGRAPH;
  tgw_kernel<<<dim3(NGRAPH * NT), dim3(64), 0, stream>>>(ei, c2, q0, out, E, ne);
}

// Round 10
// 206.006 us; speedup vs baseline: 1.3368x; 1.0786x over previous
//
#include <hip/hip_runtime.h>

#define NGRAPH 256
#define NN     128   // nodes per graph
#define NT     16    // templates
#define NM     10    // template nodes
#define OUTER_IT 5
#define SINK_IT  20

// K = exp(-20*tens) = exp2(-20*log2(e)*tens)
#define SC1  28.85390081777927f    // 20*log2(e)
#define SC2  57.70780163555854f    // 40*log2(e)

typedef unsigned long long u64;
typedef float v2f __attribute__((ext_vector_type(2)));
typedef float v4f __attribute__((ext_vector_type(4)));

static __device__ __forceinline__ v2f pkfma(v2f a, v2f b, v2f c) {
  return __builtin_elementwise_fma(a, b, c);
}
static __device__ __forceinline__ v2f bc2(float s) { return (v2f){s, s}; }

// DPP xor-butterfly add within a 16-lane row (masks {1,2,7,15} span (Z2)^4).
template <int CTRL>
__device__ __forceinline__ float dpp_add(float a) {
  int t = __builtin_amdgcn_update_dpp(0, __float_as_int(a), CTRL, 0xf, 0xf, true);
  return a + __int_as_float(t);
}
// Sum over each 32-lane group; result broadcast to all lanes of the group.
__device__ __forceinline__ float allsum32(float x) {
  x = dpp_add<0xB1>(x);    // quad_perm xor 1
  x = dpp_add<0x4E>(x);    // quad_perm xor 2
  x = dpp_add<0x141>(x);   // row_half_mirror: xor 7
  x = dpp_add<0x140>(x);   // row_mirror: xor 15
  int sw = __builtin_amdgcn_ds_swizzle(__float_as_int(x), 0x401F); // xor 16
  return x + __int_as_float(sw);
}

// 32 lanes per (graph b, template t) pair, 2 pairs per 64-thread single-wave
// block. Lane owns 4 rows r = sub + 32*c. Adjacency: LDS bitmask (shared).
// P: LDS fp32, row stride 12 floats. fp32 math packed 2-wide over the
// 10-column axis. Sinkhorn in scaled form: Khat = K*(q/pw) for the u-step,
// plain K for column sums; uhat/vhat are pure reciprocals (no q/pw muls).
__global__ __launch_bounds__(64, 2)
void tgw_kernel(const int* __restrict__ ei,
                const float* __restrict__ tadj,
                const float* __restrict__ q0g,
                float* __restrict__ out,
                int E, int ne) {
  const int lane = threadIdx.x;
  const int p    = lane >> 5;        // pair slot 0/1
  const int sub  = lane & 31;
  const int b    = blockIdx.x >> 3;
  const int t0   = (blockIdx.x & 7) * 2;   // templates t0, t0+1

  __shared__ __align__(16) unsigned adj[NN][4];    // 2 KB
  __shared__ __align__(16) float Pls[2][NN][12];   // 12 KB
  __shared__ __align__(16) v2f C2T[2][NM][6];      // SC2*C2, [m][jpair], row 48B
  __shared__ float q0s[2][NM];

  // ---- stage ----
  for (int i = lane; i < NN * 4; i += 64) (&adj[0][0])[i] = 0u;
  // C2T[tt][m][jp] = SC2 * { C2[2jp][m], C2[2jp+1][m] }  (transposed pairs)
  for (int i = lane; i < 2 * NM * 5; i += 64) {
    int tt = i / 50, r = i % 50, m = r / 5, jp = r % 5;
    const float* bp = tadj + (t0 + tt) * NM * NM + m;
    C2T[tt][m][jp] = (v2f){bp[(2 * jp) * NM], bp[(2 * jp + 1) * NM]} * SC2;
  }
  if (lane < 2 * NM) q0s[lane / NM][lane % NM] = q0g[t0 * NM + lane];
  __syncthreads();

  // symmetric 0/1 adjacency from the edge list (dups/self-loops harmless)
  const int* srcp = ei;
  const int* dstp = ei + E;
  const int ebase = b * ne;
  for (int e = lane; e < ne; e += 64) {
    int s = srcp[ebase + e] & (NN - 1);
    int d = dstp[ebase + e] & (NN - 1);
    atomicOr(&adj[s][d >> 5], 1u << (d & 31));
    atomicOr(&adj[d][s >> 5], 1u << (s & 31));
  }
  __syncthreads();

  // ---- per-pair constants ----
  float qv[NM];
  {
    float mx = q0s[p][0];
    #pragma unroll
    for (int j = 1; j < NM; ++j) mx = fmaxf(mx, q0s[p][j]);
    float s = 0.f;
    #pragma unroll
    for (int j = 0; j < NM; ++j) { qv[j] = __expf(q0s[p][j] - mx); s += qv[j]; }
    float inv = __builtin_amdgcn_rcpf(s);
    #pragma unroll
    for (int j = 0; j < NM; ++j) qv[j] *= inv;
  }
  v2f q2[5], qt2[5], vh0[5];
  const float pw = 1.0f / 128.0f;
  #pragma unroll
  for (int jp = 0; jp < 5; ++jp) {
    q2[jp]  = (v2f){qv[2 * jp], qv[2 * jp + 1]};
    qt2[jp] = q2[jp] * 128.0f;                       // q/pw
    vh0[jp] = (v2f){pw * __builtin_amdgcn_rcpf(q2[jp].x),
                    pw * __builtin_amdgcn_rcpf(q2[jp].y)};  // vhat for v=1
  }

  // fq2[jp] = -SC1*f2q pairs; qC2T[jp] = sum_m q[m]*C2T[m][jp] (o=0 analytic)
  v2f fq2[5], qC2T[5];
  {
    #pragma unroll
    for (int jp = 0; jp < 5; ++jp) { fq2[jp] = (v2f){0.f, 0.f}; qC2T[jp] = (v2f){0.f, 0.f}; }
    #pragma unroll
    for (int m = 0; m < NM; ++m) {
      float qm = (m & 1) ? q2[m >> 1].y : q2[m >> 1].x;
      v2f qb = bc2(qm);
      #pragma unroll
      for (int jp = 0; jp < 5; ++jp) {
        v2f c = C2T[p][m][jp];
        fq2[jp]  = pkfma(c * c, qb, fq2[jp]);
        qC2T[jp] = pkfma(c, qb, qC2T[jp]);
      }
    }
    const float f = -1.0f / (4.0f * SC1);   // -SC1/SC2^2
    #pragma unroll
    for (int jp = 0; jp < 5; ++jp) fq2[jp] *= f;
  }

  float f1p[4], m1f1[4];
  #pragma unroll
  for (int c = 0; c < 4; ++c) {
    uint4 mm = *(const uint4*)&adj[sub + 32 * c][0];
    u64 m0 = mm.x | ((u64)mm.y << 32), m1 = mm.z | ((u64)mm.w << 32);
    f1p[c]  = (float)(__popcll(m0) + __popcll(m1)) * pw;   // C1*C1 == C1
    m1f1[c] = -SC1 * f1p[c];
  }

  const float* Pbase = &Pls[p][0][0];
  // sparse gather S = (C1 @ P)[row r]; m0/m1 chains interleaved for ILP
  auto gatherRow = [&](int r, v2f* S2) {
    uint4 mm = *(const uint4*)&adj[r][0];
    u64 m0 = mm.x | ((u64)mm.y << 32), m1 = mm.z | ((u64)mm.w << 32);
    #pragma unroll
    for (int h = 0; h < 5; ++h) S2[h] = (v2f){0.f, 0.f};
    while (m0 && m1) {
      int k0 = (int)__builtin_ctzll(m0); m0 &= m0 - 1;
      int k1 = 64 + (int)__builtin_ctzll(m1); m1 &= m1 - 1;
      const float* r0 = Pbase + k0 * 12;
      const float* r1 = Pbase + k1 * 12;
      v4f A0 = *(const v4f*)r0; v4f B0 = *(const v4f*)(r0 + 4); v2f C0 = *(const v2f*)(r0 + 8);
      v4f A1 = *(const v4f*)r1; v4f B1 = *(const v4f*)(r1 + 4); v2f C1 = *(const v2f*)(r1 + 8);
      S2[0] += A0.xy; S2[1] += A0.zw; S2[2] += B0.xy; S2[3] += B0.zw; S2[4] += C0;
      S2[0] += A1.xy; S2[1] += A1.zw; S2[2] += B1.xy; S2[3] += B1.zw; S2[4] += C1;
    }
    while (m0) {
      int k = (int)__builtin_ctzll(m0); m0 &= m0 - 1;
      const float* row = Pbase + k * 12;
      v4f A = *(const v4f*)row; v4f B = *(const v4f*)(row + 4); v2f C = *(const v2f*)(row + 8);
      S2[0] += A.xy; S2[1] += A.zw; S2[2] += B.xy; S2[3] += B.zw; S2[4] += C;
    }
    while (m1) {
      int k = 64 + (int)__builtin_ctzll(m1); m1 &= m1 - 1;
      const float* row = Pbase + k * 12;
      v4f A = *(const v4f*)row; v4f B = *(const v4f*)(row + 4); v2f C = *(const v2f*)(row + 8);
      S2[0] += A.xy; S2[1] += A.zw; S2[2] += B.xy; S2[3] += B.zw; S2[4] += C;
    }
  };

  // arg2[c][jp] = -SC1*tens (packed over jpairs), from S2 per row
  auto costFromS = [&](v2f Sm[4][5], v2f arg2[4][5]) {
    #pragma unroll
    for (int c = 0; c < 4; ++c)
      #pragma unroll
      for (int jp = 0; jp < 5; ++jp) arg2[c][jp] = fq2[jp] + bc2(m1f1[c]);
    #pragma unroll
    for (int m = 0; m < NM; ++m) {
      v4f X = *(const v4f*)&C2T[p][m][0];
      v4f Y = *(const v4f*)&C2T[p][m][2];
      v2f Z = *(const v2f*)&C2T[p][m][4];
      #pragma unroll
      for (int c = 0; c < 4; ++c) {
        float sv = (m & 1) ? Sm[c][m >> 1].y : Sm[c][m >> 1].x;
        v2f sb = bc2(sv);
        arg2[c][0] = pkfma(sb, X.xy, arg2[c][0]);
        arg2[c][1] = pkfma(sb, X.zw, arg2[c][1]);
        arg2[c][2] = pkfma(sb, Y.xy, arg2[c][2]);
        arg2[c][3] = pkfma(sb, Y.zw, arg2[c][3]);
        arg2[c][4] = pkfma(sb, Z,    arg2[c][4]);
      }
    }
  };

  v2f K2[4][5], Kh2[4][5], vh[5], arg2[4][5];
  float uu[4];   // uhat = rcp(Khat vhat)

  for (int o = 0; o < OUTER_IT; ++o) {
    // ---- cost -> arg2 -> K = exp2(arg), Khat = K * q/pw ----
    if (o == 0) {
      #pragma unroll
      for (int c = 0; c < 4; ++c) {
        v2f fb = bc2(f1p[c]);
        v2f ob = bc2(m1f1[c]);
        #pragma unroll
        for (int jp = 0; jp < 5; ++jp)
          arg2[c][jp] = pkfma(fb, qC2T[jp], fq2[jp] + ob);
      }
    } else {
      v2f Sm[4][5];
      #pragma unroll
      for (int c = 0; c < 4; ++c) gatherRow(sub + 32 * c, Sm[c]);
      costFromS(Sm, arg2);
    }
    #pragma unroll
    for (int c = 0; c < 4; ++c)
      #pragma unroll
      for (int jp = 0; jp < 5; ++jp) {
        K2[c][jp] = (v2f){__builtin_amdgcn_exp2f(arg2[c][jp].x),
                          __builtin_amdgcn_exp2f(arg2[c][jp].y)};
        Kh2[c][jp] = K2[c][jp] * qt2[jp];
      }

    // ---- Sinkhorn, scaled form (vhat starts at pw/q == v=1) ----
    #pragma unroll
    for (int jp = 0; jp < 5; ++jp) vh[jp] = vh0[jp];
    for (int it = 0; it < SINK_IT; ++it) {
      #pragma unroll
      for (int c = 0; c < 4; ++c) {
        v2f d2 = Kh2[c][0] * vh[0];
        d2 = pkfma(Kh2[c][1], vh[1], d2);
        d2 = pkfma(Kh2[c][2], vh[2], d2);
        d2 = pkfma(Kh2[c][3], vh[3], d2);
        d2 = pkfma(Kh2[c][4], vh[4], d2);
        uu[c] = __builtin_amdgcn_rcpf(d2.x + d2.y);
      }
      #pragma unroll
      for (int jp = 0; jp < 5; ++jp) {
        v2f w2 = K2[0][jp] * bc2(uu[0]);
        w2 = pkfma(K2[1][jp], bc2(uu[1]), w2);
        w2 = pkfma(K2[2][jp], bc2(uu[2]), w2);
        w2 = pkfma(K2[3][jp], bc2(uu[3]), w2);
        float cx = allsum32(w2.x);
        float cy = allsum32(w2.y);
        vh[jp] = (v2f){__builtin_amdgcn_rcpf(cx), __builtin_amdgcn_rcpf(cy)};
      }
    }

    // ---- P = pw * diag(uhat) Khat diag(vhat) -> LDS ----
    __syncthreads();   // single-wave block: drains prior LDS reads
    #pragma unroll
    for (int c = 0; c < 4; ++c) {
      v2f ub = bc2(pw * uu[c]);
      v2f x0 = Kh2[c][0] * ub * vh[0];
      v2f x1 = Kh2[c][1] * ub * vh[1];
      v2f x2 = Kh2[c][2] * ub * vh[2];
      v2f x3 = Kh2[c][3] * ub * vh[3];
      v2f x4 = Kh2[c][4] * ub * vh[4];
      float* row = &Pls[p][sub + 32 * c][0];
      *(v4f*)row       = (v4f){x0.x, x0.y, x1.x, x1.y};
      *(v4f*)(row + 4) = (v4f){x2.x, x2.y, x3.x, x3.y};
      *(v2f*)(row + 8) = x4;
    }
    __syncthreads();
  }

  // ---- GW = sum_ij tens(P)_ij * P_ij,  tens = arg * (-1/SC1) ----
  float acc;
  {
    v2f Sm[4][5];
    #pragma unroll
    for (int c = 0; c < 4; ++c) gatherRow(sub + 32 * c, Sm[c]);
    costFromS(Sm, arg2);
    const v2f nf = bc2(-1.0f / SC1);
    v2f acc2 = (v2f){0.f, 0.f};
    #pragma unroll
    for (int c = 0; c < 4; ++c) {
      v2f ub = bc2(pw * uu[c]);
      #pragma unroll
      for (int jp = 0; jp < 5; ++jp) {
        v2f Pv = Kh2[c][jp] * ub * vh[jp];
        acc2 = pkfma(arg2[c][jp] * nf, Pv, acc2);
      }
    }
    acc = acc2.x + acc2.y;
  }
  float total = allsum32(acc);
  if (sub == 0) out[b * NT + t0 + p] = total;
}

extern "C" void kernel_launch(void* const* d_in, const int* in_sizes, int n_in,
                              void* d_out, int out_size, void* d_ws, size_t ws_size,
                              hipStream_t stream) {
  // inputs: 0 x(f32, unused) 1 edge_index(int32) 2 batch(int32, unused)
  //         3 tplt_adjacencies(f32) 4 tplt_features(f32, unused) 5 q0(f32)
  const int* ei   = (const int*)d_in[1];
  const float* c2 = (const float*)d_in[3];
  const float* q0 = (const float*)d_in[5];
  float* out      = (float*)d_out;
  const int E  = in_sizes[1] / 2;
  const int ne = E / NGRAPH;
  tgw_kernel<<<dim3(NGRAPH * 8), dim3(64), 0, stream>>>(ei, c2, q0, out, E, ne);
}